// Round 11
// baseline (56.259 us; speedup 1.0000x reference)
//
#include <hip/hip_runtime.h>

// DirectVG: batched progressive box adjustment.
// boxes [B,N,4] f32, gt [B,M,4] f32 -> all_boxes [B,6,N,4] ++ all_sims [B,6,N,M]
//
// Structure: 2 lanes per row, 32 rows per wave. p = lane&1:
//   p=0 -> m 0..51  (13 aligned quads), p=1 -> m 52..99 (12 aligned quads).
// Per chunk: 4 lgt b128 broadcast reads (2 distinct addrs/instr = free),
// 4 IoUs, one direct float4 store (64 lanes -> 1KB/instr; write-once region,
// L2 assembles full lines; stores interleave with compute = drain overlap).
// Argmax: in-lane ascending-m strict '>' then one shfl_xor(1) pair-reduce
// (tie -> smaller m) == jnp.argmax first-occurrence. Boxes: even lanes store
// row float4 (512B dense). LDS = 1.6KB, no transpose tile, no syncthreads in
// the loop. (R9 lesson: no nontemporal stores -- they bypass L2 write
// combining and amplify HBM writes 1.7x.)

#define BB 64
#define NN 1000
#define MM 100
#define NITER 5

__global__ __launch_bounds__(128) void dvg_kernel(
    const float* __restrict__ boxes, const float* __restrict__ gt,
    float* __restrict__ out) {
  __shared__ float4 lgt[MM];  // 1.6 KB

  const int tid = threadIdx.x;
  const int lane = tid & 63;
  const int p = lane & 1;        // m-half
  const int i = tid >> 1;        // row within block (0..63)
  const int b = blockIdx.x >> 4; // 16 blocks per batch
  const int n = (blockIdx.x & 15) * 64 + i;
  const bool vrow = n < NN;           // rows 1000..1023 masked
  const int nc = vrow ? n : NN - 1;   // clamp tail loads

  for (int t = tid; t < MM; t += 128)
    lgt[t] = reinterpret_cast<const float4*>(gt)[b * MM + t];
  __syncthreads();

  const float4 bx = reinterpret_cast<const float4*>(boxes)[b * NN + nc];
  float b0 = bx.x, b1 = bx.y, b2 = bx.z, b3 = bx.w;  // same in both p-lanes

  float* __restrict__ outB = out;                            // [B,6,N,4]
  float* __restrict__ outS = out + (size_t)BB * 6 * NN * 4;  // [B,6,N,M]

  const int mbase = p ? 52 : 0;  // lane's first m (13 quads p=0, 12 p=1)

  for (int it = 0;; ++it) {
    float area = (b2 - b0) * (b3 - b1);
    asm("" : "+v"(area));

    float best = -1.0f;
    int bim = 0;
    float* __restrict__ osr = outS + ((size_t)(b * 6 + it) * NN + n) * MM + mbase;

#pragma unroll
    for (int c = 0; c < 13; ++c) {
      if (p == 0 || c < 12) {  // odd lanes have 12 quads
        const int ms = mbase + 4 * c;
        float4 d;
#pragma unroll
        for (int u = 0; u < 4; ++u) {
          const float4 q = lgt[ms + u];  // 2 distinct addrs/instr: free
          float ag = (q.z - q.x) * (q.w - q.y);
          asm("" : "+v"(ag));
          const float w = fmaxf(fminf(b2, q.z) - fmaxf(b0, q.x), 0.0f);
          const float h = fmaxf(fminf(b3, q.w) - fmaxf(b1, q.y), 0.0f);
          float inter = w * h;
          asm("" : "+v"(inter));
          const float uni = (area + ag) - inter;
          const float val = inter * __builtin_amdgcn_rcpf(uni);
          (&d.x)[u] = val;
          const bool t = val > best;  // strict >: first occurrence in-lane
          best = t ? val : best;
          bim = t ? ms + u : bim;
        }
        if (vrow) *reinterpret_cast<float4*>(osr + 4 * c) = d;
      }
    }

    // boxes out: even lanes store their row's box (512B dense per wave)
    if (vrow && p == 0) {
      reinterpret_cast<float4*>(outB)[(size_t)(b * 6 + it) * NN + n] =
          make_float4(b0, b1, b2, b3);
    }
    if (it == NITER) break;

    // pair-reduce argmax (tie -> smaller m; halves are disjoint ranges)
    {
      const float ov = __shfl_xor(best, 1, 64);
      const int obi = __shfl_xor(bim, 1, 64);
      const bool t = (ov > best) || (ov == best && obi < bim);
      best = t ? ov : best;
      bim = t ? obi : bim;
    }

    const float4 gg = lgt[bim];  // pair-uniform gather, 1 per iter
    const float dcx = (gg.x + gg.z) * 0.5f - (b0 + b2) * 0.5f;
    const float dcy = (gg.y + gg.w) * 0.5f - (b1 + b3) * 0.5f;
    const float dsx = (gg.z - gg.x) - (b2 - b0);
    const float dsy = (gg.w - gg.y) - (b3 - b1);
    float px = 0.45f * dcx;
    asm("" : "+v"(px));
    float py = 0.45f * dcy;
    asm("" : "+v"(py));
    float qx = 0.4f * (dsx - dcx);
    asm("" : "+v"(qx));
    float qy = 0.4f * (dsy - dcy);
    asm("" : "+v"(qy));
    b0 = b0 + px;
    b1 = b1 + py;
    b2 = (b2 + px) + qx;
    b3 = (b3 + py) + qy;
  }
}

extern "C" void kernel_launch(void* const* d_in, const int* in_sizes, int n_in,
                              void* d_out, int out_size, void* d_ws,
                              size_t ws_size, hipStream_t stream) {
  const float* boxes = (const float*)d_in[0];
  const float* gt = (const float*)d_in[1];
  float* out = (float*)d_out;
  // 16 blocks/batch x 64 rows (2 waves) = 1024 row-slots >= 1000
  dvg_kernel<<<BB * 16, 128, 0, stream>>>(boxes, gt, out);
}

// Round 12
// 37.170 us; speedup vs baseline: 1.5136x; 1.5136x over previous
//
#include <hip/hip_runtime.h>

// DirectVG: batched progressive box adjustment.
// boxes [B,N,4] f32, gt [B,M,4] f32 -> all_boxes [B,6,N,4] ++ all_sims [B,6,N,M]
//
// R4's proven pipeline (IoU+argmax -> LDS tile transpose -> coalesced
// dwordx4 stores) at HALF rows/wave for 2x occupancy:
//   wave = 8 rows x 8 m-groups; r = lane&7, g = lane>>3.
//   g<4: 13 elems from m=13g; g>=4: 12 elems from m=52+12(g-4).
//   2048 blocks (8/CU) x 4 waves = 32 waves/CU (launch_bounds(256,8)).
// Tile stride 104 floats: b128-aligned reads, <=4-way banks.
// Argmax: in-lane ascending-m strict '>', 3-step shfl over the row's 8
// lanes (tie -> smaller m) == jnp.argmax. Stores: 128B segments per row.
// (R9 lesson: NO nontemporal stores -- 1.7x HBM write amplification.)

#define BB 64
#define NN 1000
#define MM 100
#define NITER 5
#define RPW 8     // rows per wave
#define SSTR 104  // tile row stride (floats): aligned + 4-way banks max

__global__ __launch_bounds__(256, 8) void dvg_kernel(
    const float* __restrict__ boxes, const float* __restrict__ gt,
    float* __restrict__ out) {
  __shared__ float4 lgt[MM];              // 1.6 KB
  __shared__ float lsims[4][RPW][SSTR];   // 13.3 KB

  const int tid = threadIdx.x;
  const int wv = tid >> 6;
  const int lane = tid & 63;
  const int r = lane & 7;   // row within wave's 8
  const int g = lane >> 3;  // m-group
  const int b = blockIdx.x >> 5;  // 32 chunk-blocks per batch
  const int n0w = (blockIdx.x & 31) * 32 + wv * RPW;  // wave's first row
  const int n = n0w + r;
  const int nc = n < NN ? n : NN - 1;  // clamp tail loads (stores masked)

  const int LEN = g < 4 ? 13 : 12;
  const int START = g < 4 ? 13 * g : 52 + 12 * (g - 4);

  for (int i = tid; i < MM; i += 256)
    lgt[i] = reinterpret_cast<const float4*>(gt)[b * MM + i];
  __syncthreads();

  // loop-invariant gt areas for this lane's elements
  float areaG[13];
#pragma unroll
  for (int j = 0; j < 13; ++j) {
    if (j < LEN) {
      const float4 q = lgt[START + j];
      float a = (q.z - q.x) * (q.w - q.y);
      asm("" : "+v"(a));
      areaG[j] = a;
    }
  }

  const float4 bx = reinterpret_cast<const float4*>(boxes)[b * NN + nc];
  float b0 = bx.x, b1 = bx.y, b2 = bx.z, b3 = bx.w;

  float* __restrict__ outB = out;                            // [B,6,N,4]
  float* __restrict__ outS = out + (size_t)BB * 6 * NN * 4;  // [B,6,N,M]

  // boxes-out transpose: target lane l=4r'+c (l<32) pulls from src r'+8c
  const int bp_addr = (((lane >> 2) + ((lane & 3) << 3)) << 2);
  const int rr = lane >> 3;       // row for read/store phases (== r)
  const int cq = lane & 7;        // quad slot within pass
  const bool rowok = (n0w + rr) < NN;
  const bool boxok = lane < 32 && (n0w + (lane >> 2)) < NN;

  for (int it = 0;; ++it) {
    float area = (b2 - b0) * (b3 - b1);
    asm("" : "+v"(area));

    // 1) IoUs + in-lane first-occurrence argmax + tile staging
    float best = -1.0f;
    int bim = 0;
    {
      float* ls = &lsims[wv][r][START];
#pragma unroll
      for (int j = 0; j < 13; ++j) {
        if (j < LEN) {
          const float4 q = lgt[START + j];
          const float ltx = fmaxf(b0, q.x), lty = fmaxf(b1, q.y);
          const float rbx = fminf(b2, q.z), rby = fminf(b3, q.w);
          const float w = fmaxf(rbx - ltx, 0.0f);
          const float h = fmaxf(rby - lty, 0.0f);
          float inter = w * h;
          asm("" : "+v"(inter));
          const float uni = (area + areaG[j]) - inter;
          const float val = inter * __builtin_amdgcn_rcpf(uni);
          ls[j] = val;
          const bool t = val > best;  // strict >: first occurrence in-lane
          best = t ? val : best;
          bim = t ? START + j : bim;
        }
      }
    }

    // 2) boxes transpose from current state
    const float tcomp = g == 0 ? b0 : (g == 1 ? b1 : (g == 2 ? b2 : b3));
    const float bt = __int_as_float(
        __builtin_amdgcn_ds_bpermute(bp_addr, __float_as_int(tcomp)));

    const size_t obase = (size_t)(b * 6 + it) * NN + n0w;

    // 3) stores: boxes (128B dense) + sims (4 passes, 128B segments/row)
    if (boxok) outB[obase * 4 + lane] = bt;
    {
      const float* lsr = &lsims[wv][0][0];
      float* os = outS + obase * MM;
#pragma unroll
      for (int i = 0; i < 4; ++i) {
        const int q = 8 * i + cq;  // quad 0..24
        if (i < 3 || cq == 0) {
          if (rowok) {
            const float4 d =
                *reinterpret_cast<const float4*>(&lsr[rr * SSTR + 4 * q]);
            *reinterpret_cast<float4*>(&os[(size_t)rr * MM + 4 * q]) = d;
          }
        }
      }
    }

    if (it == NITER) break;

    // 4) argmax across the row's 8 g-lanes (tie -> smaller global m)
#pragma unroll
    for (int off = 8; off <= 32; off <<= 1) {
      const float ov = __shfl_xor(best, off, 64);
      const int obi = __shfl_xor(bim, off, 64);
      const bool t = (ov > best) || (ov == best && obi < bim);
      best = t ? ov : best;
      bim = t ? obi : bim;
    }

    const float4 gg = lgt[bim];  // 8 distinct addrs/wave -> cheap gather
    const float dcx = (gg.x + gg.z) * 0.5f - (b0 + b2) * 0.5f;
    const float dcy = (gg.y + gg.w) * 0.5f - (b1 + b3) * 0.5f;
    const float dsx = (gg.z - gg.x) - (b2 - b0);
    const float dsy = (gg.w - gg.y) - (b3 - b1);
    float px = 0.45f * dcx;
    asm("" : "+v"(px));
    float py = 0.45f * dcy;
    asm("" : "+v"(py));
    float qx = 0.4f * (dsx - dcx);
    asm("" : "+v"(qx));
    float qy = 0.4f * (dsy - dcy);
    asm("" : "+v"(qy));
    b0 = b0 + px;
    b1 = b1 + py;
    b2 = (b2 + px) + qx;
    b3 = (b3 + py) + qy;
  }
}

extern "C" void kernel_launch(void* const* d_in, const int* in_sizes, int n_in,
                              void* d_out, int out_size, void* d_ws,
                              size_t ws_size, hipStream_t stream) {
  const float* boxes = (const float*)d_in[0];
  const float* gt = (const float*)d_in[1];
  float* out = (float*)d_out;
  // 64 batches x 32 chunks = 2048 blocks; 4 waves x 8 rows = 32 rows/block
  dvg_kernel<<<BB * 32, 256, 0, stream>>>(boxes, gt, out);
}